// Round 4
// baseline (9593.771 us; speedup 1.0000x reference)
//
#include <hip/hip_runtime.h>
#include <math.h>

typedef unsigned long long u64;
typedef unsigned int u32;
typedef unsigned int u32x4 __attribute__((ext_vector_type(4)));

#define S_LEN 1024
#define E_DIM 512
#define H_DIM 512
#define G3    1536   // 3*H
#define D_DIM 1024

#define NCHAIN 4
#define WPC    32     // member workgroups per GRU chain
#define NBLK   1024   // launched blocks for the scan (claim-or-exit pool)
#define SPIN_L2 32    // L2 poll attempts before falling back to LLC copy

// ---------------------------------------------------------------------------
// Phase 1: gi[p][t][j] = bih_p[j] + sum_k emb[sent[t],k] * Wih_p[j,k]
// Tiled fp32 GEMM, TM=TN=64, BK=32, 256 threads, 4x4 micro-tile per thread.
// (unchanged from R2 — proven)
// ---------------------------------------------------------------------------
#define TM 64
#define TN 64
#define BK 32

__global__ __launch_bounds__(256) void gi_gemm_kernel(
    const int* __restrict__ sent, const float* __restrict__ emb,
    const float* __restrict__ Wih0, const float* __restrict__ bih0,
    const float* __restrict__ Wih1, const float* __restrict__ bih1,
    const float* __restrict__ Wih2, const float* __restrict__ bih2,
    const float* __restrict__ Wih3, const float* __restrict__ bih3,
    float* __restrict__ gi)
{
    __shared__ float As[BK][TM + 1];
    __shared__ float Bs[BK][TN + 1];
    __shared__ int   rows[TM];

    const int blocks_t = S_LEN / TM;   // 16
    const int blocks_j = G3 / TN;      // 24
    int b   = blockIdx.x;
    int p   = b / (blocks_t * blocks_j);
    int rem = b % (blocks_t * blocks_j);
    int bt  = rem / blocks_j;
    int bj  = rem % blocks_j;

    const float* Wih = (p == 0) ? Wih0 : (p == 1) ? Wih1 : (p == 2) ? Wih2 : Wih3;
    const float* bih = (p == 0) ? bih0 : (p == 1) ? bih1 : (p == 2) ? bih2 : bih3;

    int tid = threadIdx.x;
    if (tid < TM) rows[tid] = sent[bt * TM + tid];
    __syncthreads();

    int tt = (tid >> 4) * 4;
    int jj = (tid & 15) * 4;
    float acc[4][4] = {{0.f}};

    int lr = tid >> 2;
    int lc = (tid & 3) * 8;

    for (int k0 = 0; k0 < E_DIM; k0 += BK) {
        const float* asrc = emb + (size_t)rows[lr] * E_DIM + (k0 + lc);
        float4 a0 = *(const float4*)asrc;
        float4 a1 = *(const float4*)(asrc + 4);
        const float* bsrc = Wih + (size_t)(bj * TN + lr) * E_DIM + (k0 + lc);
        float4 b0 = *(const float4*)bsrc;
        float4 b1 = *(const float4*)(bsrc + 4);

        As[lc+0][lr]=a0.x; As[lc+1][lr]=a0.y; As[lc+2][lr]=a0.z; As[lc+3][lr]=a0.w;
        As[lc+4][lr]=a1.x; As[lc+5][lr]=a1.y; As[lc+6][lr]=a1.z; As[lc+7][lr]=a1.w;
        Bs[lc+0][lr]=b0.x; Bs[lc+1][lr]=b0.y; Bs[lc+2][lr]=b0.z; Bs[lc+3][lr]=b0.w;
        Bs[lc+4][lr]=b1.x; Bs[lc+5][lr]=b1.y; Bs[lc+6][lr]=b1.z; Bs[lc+7][lr]=b1.w;
        __syncthreads();

        #pragma unroll
        for (int kk = 0; kk < BK; ++kk) {
            float av[4], bv[4];
            #pragma unroll
            for (int e = 0; e < 4; ++e) { av[e] = As[kk][tt+e]; bv[e] = Bs[kk][jj+e]; }
            #pragma unroll
            for (int i = 0; i < 4; ++i)
                #pragma unroll
                for (int j2 = 0; j2 < 4; ++j2)
                    acc[i][j2] = fmaf(av[i], bv[j2], acc[i][j2]);
        }
        __syncthreads();
    }

    float* gout = gi + (size_t)p * S_LEN * G3;
    int jbase = bj * TN + jj;
    float bb0 = bih[jbase+0], bb1 = bih[jbase+1], bb2 = bih[jbase+2], bb3 = bih[jbase+3];
    #pragma unroll
    for (int i = 0; i < 4; ++i) {
        int t = bt * TM + tt + i;
        float4 v = make_float4(acc[i][0]+bb0, acc[i][1]+bb1, acc[i][2]+bb2, acc[i][3]+bb3);
        *(float4*)(gout + (size_t)t * G3 + jbase) = v;
    }
}

// ---------------------------------------------------------------------------
// Cache-scope primitives.
// sc0 = L1-bypass, served by the XCD-local L2 (fast path; valid only because
// chain membership is XCD-pure by construction).
// LLC copy written with relaxed AGENT atomics (sc0 sc1) = R2-proven fallback.
// Tag rides atomically with the value in one 8B slot -> fence-free protocol.
// ---------------------------------------------------------------------------
__device__ __forceinline__ void l2_store_u64(u64* p, u64 v) {
    asm volatile("global_store_dwordx2 %0, %1, off sc0"
                 :: "v"((u64)p), "v"(v) : "memory");
}
__device__ __forceinline__ u32x4 l2_load_u128(const u64* p) {
    u32x4 v;
    asm volatile("global_load_dwordx4 %0, %1, off sc0\n\t"
                 "s_waitcnt vmcnt(0)"
                 : "=v"(v) : "v"((u64)p) : "memory");
    return v;
}

struct SeatReg { unsigned cnt[16]; };   // 64 B, zeroed each launch

// ---------------------------------------------------------------------------
// Phase 2: 4 independent GRU recurrences, persistent, claim-or-exit staffing.
// Block reads its physical XCD (HW_REG_XCC_ID, HW-verified). XCD c<4 blocks
// claim one of chain c's 32 seats (LLC atomic); losers + XCD>=4 exit. Chains
// are XCD-pure by construction -> h exchange through the XCD-local L2 (sc0
// tagged slots). Writers dual-publish to an LLC copy; readers fall back to
// polling the LLC copy after SPIN_L2 misses, so a placement/semantics
// surprise degrades to ~R2 speed instead of hanging.
// Block = 256 thr; seat w owns h indices [16w,16w+16); wave wv computes 4
// of them (lane<4); Whh rows in registers (96 floats/thread).
// ---------------------------------------------------------------------------
__global__ __launch_bounds__(256) void gru_scan_kernel(
    const float* __restrict__ Whh0, const float* __restrict__ bhh0,
    const float* __restrict__ Whh1, const float* __restrict__ bhh1,
    const float* __restrict__ Whh2, const float* __restrict__ bhh2,
    const float* __restrict__ Whh3, const float* __restrict__ bhh3,
    const float* __restrict__ gi,
    u64* __restrict__ hp2,          // [4][2][512] tagged slots, L2 fast path
    u64* __restrict__ hpc,          // [4][2][512] tagged slots, LLC fallback
    float* __restrict__ hfin,       // [4][512] final h, agent-published
    SeatReg* __restrict__ reg)      // zeroed each launch
{
    __shared__ float lds_h[2][H_DIM];
    __shared__ int sh_role[2];      // chain, seat

    if (threadIdx.x == 0) {
        unsigned xcd;
        asm volatile("s_getreg_b32 %0, hwreg(HW_REG_XCC_ID)" : "=s"(xcd));
        xcd &= 7u;
        int myc = -1, myw = -1;
        if (xcd < (unsigned)NCHAIN) {
            unsigned s = __hip_atomic_fetch_add(&reg->cnt[xcd], 1u,
                             __ATOMIC_RELAXED, __HIP_MEMORY_SCOPE_AGENT);
            if (s < (unsigned)WPC) { myc = (int)xcd; myw = (int)s; }
        }
        sh_role[0] = myc; sh_role[1] = myw;
    }
    __syncthreads();
    int c = sh_role[0], w = sh_role[1];
    if (c < 0) return;

    const float* Whh = (c==0)?Whh0:(c==1)?Whh1:(c==2)?Whh2:Whh3;
    const float* bhh = (c==0)?bhh0:(c==1)?bhh1:(c==2)?bhh2:bhh3;
    const float* gic = gi + (size_t)c * S_LEN * G3;
    u64* h2 = hp2 + (size_t)c * 2 * H_DIM;
    u64* hc = hpc + (size_t)c * 2 * H_DIM;
    float* hfc = hfin + (size_t)c * H_DIM;
    const bool fwd = ((c & 1) == 0);   // chains 0 (ctx_f), 2 (qry_f) forward

    int tid  = threadIdx.x;
    int wv   = tid >> 6;
    int lane = tid & 63;
    int base_i = w * 16 + wv * 4;

    // Whh fragment in registers: wreg[g][m][e] = Whh[g*512+base_i+m][lane*8+e]
    float wreg[3][4][8];
    #pragma unroll
    for (int g = 0; g < 3; ++g)
        #pragma unroll
        for (int m = 0; m < 4; ++m) {
            const float* src = Whh + (size_t)(g * H_DIM + base_i + m) * H_DIM + lane * 8;
            float4 v0 = *(const float4*)src;
            float4 v1 = *(const float4*)(src + 4);
            wreg[g][m][0]=v0.x; wreg[g][m][1]=v0.y; wreg[g][m][2]=v0.z; wreg[g][m][3]=v0.w;
            wreg[g][m][4]=v1.x; wreg[g][m][5]=v1.y; wreg[g][m][6]=v1.z; wreg[g][m][7]=v1.w;
        }

    int my_i = base_i + lane;   // meaningful for lane < 4
    float bh_r=0.f, bh_z=0.f, bh_n=0.f;
    float gr=0.f, gz=0.f, gn=0.f;
    if (lane < 4) {
        bh_r = bhh[my_i]; bh_z = bhh[H_DIM + my_i]; bh_n = bhh[2*H_DIM + my_i];
        int t0 = fwd ? 0 : (S_LEN - 1);
        const float* g0 = gic + (size_t)t0 * G3;
        gr = g0[my_i]; gz = g0[H_DIM + my_i]; gn = g0[2*H_DIM + my_i];
    }

    lds_h[0][tid]       = 0.f;   // h_0 = 0
    lds_h[0][tid + 256] = 0.f;

    // Thread tid ferries the slot pair {2*tid, 2*tid+1}; owned iff both fall
    // in [16w,16w+16) <=> (tid>>3)==w (pair never straddles an owner range).
    const bool own = ((tid >> 3) == w);

    for (int s = 0; s < S_LEN; ++s) {
        int pb = s & 1;
        if (s > 0 && !own) {
            const u64* src2 = h2 + (size_t)pb * H_DIM + 2 * tid;
            const u64* srcc = hc + (size_t)pb * H_DIM + 2 * tid;
            bool d0 = false, d1 = false;
            int spins = 0;
            while (!(d0 && d1)) {
                if (spins < SPIN_L2) {
                    u32x4 v = l2_load_u128(src2);
                    if (!d0 && v.y == (u32)s) { lds_h[pb][2*tid]   = __uint_as_float(v.x); d0 = true; }
                    if (!d1 && v.w == (u32)s) { lds_h[pb][2*tid+1] = __uint_as_float(v.z); d1 = true; }
                    ++spins;
                } else {   // LLC fallback (dual-published by writers)
                    if (!d0) {
                        u64 v = __hip_atomic_load(srcc + 0, __ATOMIC_RELAXED, __HIP_MEMORY_SCOPE_AGENT);
                        if ((u32)(v >> 32) == (u32)s) { lds_h[pb][2*tid]   = __uint_as_float((u32)v); d0 = true; }
                    }
                    if (!d1) {
                        u64 v = __hip_atomic_load(srcc + 1, __ATOMIC_RELAXED, __HIP_MEMORY_SCOPE_AGENT);
                        if ((u32)(v >> 32) == (u32)s) { lds_h[pb][2*tid+1] = __uint_as_float((u32)v); d1 = true; }
                    }
                }
            }
        }
        __syncthreads();

        float hf[8];
        #pragma unroll
        for (int e = 0; e < 8; ++e) hf[e] = lds_h[pb][lane * 8 + e];

        float acc[3][4];
        #pragma unroll
        for (int g = 0; g < 3; ++g)
            #pragma unroll
            for (int m = 0; m < 4; ++m) {
                float a = 0.f;
                #pragma unroll
                for (int e = 0; e < 8; ++e) a = fmaf(wreg[g][m][e], hf[e], a);
                acc[g][m] = a;
            }
        #pragma unroll
        for (int off = 32; off >= 1; off >>= 1)
            #pragma unroll
            for (int g = 0; g < 3; ++g)
                #pragma unroll
                for (int m = 0; m < 4; ++m)
                    acc[g][m] += __shfl_xor(acc[g][m], off, 64);

        if (lane < 4) {
            float ar = (lane==0)?acc[0][0]:(lane==1)?acc[0][1]:(lane==2)?acc[0][2]:acc[0][3];
            float az = (lane==0)?acc[1][0]:(lane==1)?acc[1][1]:(lane==2)?acc[1][2]:acc[1][3];
            float an = (lane==0)?acc[2][0]:(lane==1)?acc[2][1]:(lane==2)?acc[2][2]:acc[2][3];
            float hv = lds_h[pb][my_i];
            float rr = 1.f / (1.f + expf(-(gr + ar + bh_r)));
            float zz = 1.f / (1.f + expf(-(gz + az + bh_z)));
            float nn = tanhf(gn + rr * (an + bh_n));
            float hn = (1.f - zz) * nn + zz * hv;
            lds_h[pb ^ 1][my_i] = hn;                 // own short-circuit
            union { float f; u32 u; } cv; cv.f = hn;
            u64 pk = ((u64)(u32)(s + 1) << 32) | (u64)cv.u;
            size_t di = (size_t)(pb ^ 1) * H_DIM + my_i;
            l2_store_u64(h2 + di, pk);                // fast path (XCD L2)
            __hip_atomic_store(hc + di, pk,           // insurance (LLC)
                               __ATOMIC_RELAXED, __HIP_MEMORY_SCOPE_AGENT);
            if (s == S_LEN - 1)
                __hip_atomic_store((u32*)&hfc[my_i], cv.u,
                                   __ATOMIC_RELAXED, __HIP_MEMORY_SCOPE_AGENT);
        }
        // Prefetch next step's gi (off critical path)
        if (lane < 4 && s + 1 < S_LEN) {
            int tn = fwd ? (s + 1) : (S_LEN - 2 - s);
            const float* gnx = gic + (size_t)tn * G3;
            gr = gnx[my_i]; gz = gnx[H_DIM + my_i]; gn = gnx[2*H_DIM + my_i];
        }
    }
}

// ---------------------------------------------------------------------------
// Phase 3a: h1 = relu(d1_w @ rep + d1_b); rep[j] = hfin[j] (chains concat).
// ---------------------------------------------------------------------------
__global__ __launch_bounds__(256) void dense1_kernel(
    const float* __restrict__ d1w, const float* __restrict__ d1b,
    const float* __restrict__ hfin, float* __restrict__ h1)
{
    int wv = threadIdx.x >> 6, lane = threadIdx.x & 63;
    int row = blockIdx.x * 4 + wv;
    const float* wr = d1w + (size_t)row * (4 * H_DIM);
    float sum = 0.f;
    #pragma unroll
    for (int q = 0; q < 32; ++q) {
        int j = lane + q * 64;
        sum = fmaf(wr[j], hfin[j], sum);
    }
    #pragma unroll
    for (int off = 32; off >= 1; off >>= 1) sum += __shfl_xor(sum, off, 64);
    if (lane == 0) h1[row] = fmaxf(sum + d1b[row], 0.f);
}

__global__ __launch_bounds__(256) void dense2_kernel(
    const float* __restrict__ d2w, const float* __restrict__ d2b,
    const float* __restrict__ h1, float* __restrict__ out)
{
    __shared__ float red[4];
    int tid = threadIdx.x, lane = tid & 63, wv = tid >> 6;
    float sum = 0.f;
    #pragma unroll
    for (int q = 0; q < 4; ++q) { int j = tid + q * 256; sum = fmaf(d2w[j], h1[j], sum); }
    #pragma unroll
    for (int off = 32; off >= 1; off >>= 1) sum += __shfl_xor(sum, off, 64);
    if (lane == 0) red[wv] = sum;
    __syncthreads();
    if (tid == 0) {
        float t = red[0] + red[1] + red[2] + red[3] + d2b[0];
        out[0] = 1.f / (1.f + expf(-t));
    }
}

// ---------------------------------------------------------------------------
extern "C" void kernel_launch(void* const* d_in, const int* in_sizes, int n_in,
                              void* d_out, int out_size, void* d_ws, size_t ws_size,
                              hipStream_t stream) {
    const int*   sent = (const int*)d_in[0];
    const float* emb  = (const float*)d_in[1];
    const float* Wih[4], *Whh[4], *bih[4], *bhh[4];
    for (int p = 0; p < 4; ++p) {
        Wih[p] = (const float*)d_in[2 + 4*p + 0];
        Whh[p] = (const float*)d_in[2 + 4*p + 1];
        bih[p] = (const float*)d_in[2 + 4*p + 2];
        bhh[p] = (const float*)d_in[2 + 4*p + 3];
    }
    const float* d1w = (const float*)d_in[18];
    const float* d1b = (const float*)d_in[19];
    const float* d2w = (const float*)d_in[20];
    const float* d2b = (const float*)d_in[21];
    float* out = (float*)d_out;

    // Workspace layout (bytes):
    //   gi   : 4*1024*1536*4 = 25165824
    //   hp2  : 4*2*512*8     = 32768   (tagged slots, L2 path; no init needed)
    //   hpc  : 4*2*512*8     = 32768   (tagged slots, LLC path; no init needed)
    //   hfin : 4*512*4       = 8192
    //   h1   : 1024*4        = 4096
    //   reg  : 64            (must be zeroed each launch)
    char* wsb = (char*)d_ws;
    float*   gi   = (float*)wsb;                       wsb += (size_t)NCHAIN * S_LEN * G3 * sizeof(float);
    u64*     hp2  = (u64*)wsb;                         wsb += (size_t)NCHAIN * 2 * H_DIM * sizeof(u64);
    u64*     hpc  = (u64*)wsb;                         wsb += (size_t)NCHAIN * 2 * H_DIM * sizeof(u64);
    float*   hfin = (float*)wsb;                       wsb += (size_t)NCHAIN * H_DIM * sizeof(float);
    float*   h1   = (float*)wsb;                       wsb += (size_t)D_DIM * sizeof(float);
    SeatReg* reg  = (SeatReg*)wsb;

    hipMemsetAsync(reg, 0, sizeof(SeatReg), stream);

    gi_gemm_kernel<<<NCHAIN * (S_LEN/TM) * (G3/TN), 256, 0, stream>>>(
        sent, emb,
        Wih[0], bih[0], Wih[1], bih[1], Wih[2], bih[2], Wih[3], bih[3], gi);

    gru_scan_kernel<<<NBLK, 256, 0, stream>>>(
        Whh[0], bhh[0], Whh[1], bhh[1], Whh[2], bhh[2], Whh[3], bhh[3],
        gi, hp2, hpc, hfin, reg);

    dense1_kernel<<<D_DIM / 4, 256, 0, stream>>>(d1w, d1b, hfin, h1);
    dense2_kernel<<<1, 256, 0, stream>>>(d2w, d2b, h1, out);
}

// Round 5
// 3578.422 us; speedup vs baseline: 2.6810x; 2.6810x over previous
//
#include <hip/hip_runtime.h>
#include <math.h>

typedef unsigned long long u64;
typedef unsigned int u32;
typedef unsigned int u32x4 __attribute__((ext_vector_type(4)));

#define S_LEN 1024
#define E_DIM 512
#define H_DIM 512
#define G3    1536   // 3*H
#define D_DIM 1024

#define NCHAIN 4
#define WPC    32    // workgroups per GRU chain (128 blocks total)

// ---------------------------------------------------------------------------
// Phase 1: gi[p][t][j] = bih_p[j] + sum_k emb[sent[t],k] * Wih_p[j,k]
// Tiled fp32 GEMM (proven R2 version, unchanged).
// ---------------------------------------------------------------------------
#define TM 64
#define TN 64
#define BK 32

__global__ __launch_bounds__(256) void gi_gemm_kernel(
    const int* __restrict__ sent, const float* __restrict__ emb,
    const float* __restrict__ Wih0, const float* __restrict__ bih0,
    const float* __restrict__ Wih1, const float* __restrict__ bih1,
    const float* __restrict__ Wih2, const float* __restrict__ bih2,
    const float* __restrict__ Wih3, const float* __restrict__ bih3,
    float* __restrict__ gi)
{
    __shared__ float As[BK][TM + 1];
    __shared__ float Bs[BK][TN + 1];
    __shared__ int   rows[TM];

    const int blocks_t = S_LEN / TM;   // 16
    const int blocks_j = G3 / TN;      // 24
    int b   = blockIdx.x;
    int p   = b / (blocks_t * blocks_j);
    int rem = b % (blocks_t * blocks_j);
    int bt  = rem / blocks_j;
    int bj  = rem % blocks_j;

    const float* Wih = (p == 0) ? Wih0 : (p == 1) ? Wih1 : (p == 2) ? Wih2 : Wih3;
    const float* bih = (p == 0) ? bih0 : (p == 1) ? bih1 : (p == 2) ? bih2 : bih3;

    int tid = threadIdx.x;
    if (tid < TM) rows[tid] = sent[bt * TM + tid];
    __syncthreads();

    int tt = (tid >> 4) * 4;
    int jj = (tid & 15) * 4;
    float acc[4][4] = {{0.f}};

    int lr = tid >> 2;
    int lc = (tid & 3) * 8;

    for (int k0 = 0; k0 < E_DIM; k0 += BK) {
        const float* asrc = emb + (size_t)rows[lr] * E_DIM + (k0 + lc);
        float4 a0 = *(const float4*)asrc;
        float4 a1 = *(const float4*)(asrc + 4);
        const float* bsrc = Wih + (size_t)(bj * TN + lr) * E_DIM + (k0 + lc);
        float4 b0 = *(const float4*)bsrc;
        float4 b1 = *(const float4*)(bsrc + 4);

        As[lc+0][lr]=a0.x; As[lc+1][lr]=a0.y; As[lc+2][lr]=a0.z; As[lc+3][lr]=a0.w;
        As[lc+4][lr]=a1.x; As[lc+5][lr]=a1.y; As[lc+6][lr]=a1.z; As[lc+7][lr]=a1.w;
        Bs[lc+0][lr]=b0.x; Bs[lc+1][lr]=b0.y; Bs[lc+2][lr]=b0.z; Bs[lc+3][lr]=b0.w;
        Bs[lc+4][lr]=b1.x; Bs[lc+5][lr]=b1.y; Bs[lc+6][lr]=b1.z; Bs[lc+7][lr]=b1.w;
        __syncthreads();

        #pragma unroll
        for (int kk = 0; kk < BK; ++kk) {
            float av[4], bv[4];
            #pragma unroll
            for (int e = 0; e < 4; ++e) { av[e] = As[kk][tt+e]; bv[e] = Bs[kk][jj+e]; }
            #pragma unroll
            for (int i = 0; i < 4; ++i)
                #pragma unroll
                for (int j2 = 0; j2 < 4; ++j2)
                    acc[i][j2] = fmaf(av[i], bv[j2], acc[i][j2]);
        }
        __syncthreads();
    }

    float* gout = gi + (size_t)p * S_LEN * G3;
    int jbase = bj * TN + jj;
    float bb0 = bih[jbase+0], bb1 = bih[jbase+1], bb2 = bih[jbase+2], bb3 = bih[jbase+3];
    #pragma unroll
    for (int i = 0; i < 4; ++i) {
        int t = bt * TM + tt + i;
        float4 v = make_float4(acc[i][0]+bb0, acc[i][1]+bb1, acc[i][2]+bb2, acc[i][3]+bb3);
        *(float4*)(gout + (size_t)t * G3 + jbase) = v;
    }
}

// ---------------------------------------------------------------------------
// Phase 2: 4 GRU recurrences, persistent, BARRIER-FREE tagged-slot sync.
//
// Medium: LLC (agent-scope, sc0 sc1) tagged 8B slots {tag=step : u32, val :
// f32} — the R2-proven protocol. Structural change vs R2: NO LDS staging and
// NO __syncthreads in the step loop. Lane l of every wave polls exactly the
// 64 B it consumes (slots 8l..8l+8, 4 x dwordx4 agent loads) straight into
// registers; the shuffle-reduce makes the wave cover all 512 h. The blend
// value h_prev[my_i] lives in a register (same thread computes my_i every
// step). Double-buffer (parity) + tag = step is overwrite-safe: a wave
// stores tag s+1 only after all its lanes consumed all tag-s slots, and any
// slot's tag-(s+2) store transitively requires every wave's tag-(s+1) store.
// 0xAA workspace poison (tag 0xAAAAAAAA) never matches s in [1,1024].
//
// Block b: chain c=b/32, seat w=b%32 owns h[16w..16w+16); wave wv's lanes
// 0-3 produce h[16w+4wv .. +4]; Whh rows in registers (96 floats/thread).
// ---------------------------------------------------------------------------
__global__ __launch_bounds__(256) void gru_scan_kernel(
    const float* __restrict__ Whh0, const float* __restrict__ bhh0,
    const float* __restrict__ Whh1, const float* __restrict__ bhh1,
    const float* __restrict__ Whh2, const float* __restrict__ bhh2,
    const float* __restrict__ Whh3, const float* __restrict__ bhh3,
    const float* __restrict__ gi,
    u64* __restrict__ hpk,          // [4][2][512] tagged slots (no init needed)
    float* __restrict__ hfin)       // [4][512] final h
{
    int b = blockIdx.x;
    int c = b / WPC;
    int w = b % WPC;
    const float* Whh = (c==0)?Whh0:(c==1)?Whh1:(c==2)?Whh2:Whh3;
    const float* bhh = (c==0)?bhh0:(c==1)?bhh1:(c==2)?bhh2:bhh3;
    const float* gic = gi + (size_t)c * S_LEN * G3;
    u64* hp = hpk + (size_t)c * 2 * H_DIM;
    float* hfc = hfin + (size_t)c * H_DIM;
    const bool fwd = ((c & 1) == 0);   // chains 0 (ctx_f), 2 (qry_f) forward

    int tid  = threadIdx.x;
    int wv   = tid >> 6;
    int lane = tid & 63;
    int base_i = w * 16 + wv * 4;

    // Whh fragment: wreg[g][m][e] = Whh[g*512 + base_i + m][lane*8 + e]
    float wreg[3][4][8];
    #pragma unroll
    for (int g = 0; g < 3; ++g)
        #pragma unroll
        for (int m = 0; m < 4; ++m) {
            const float* src = Whh + (size_t)(g * H_DIM + base_i + m) * H_DIM + lane * 8;
            float4 v0 = *(const float4*)src;
            float4 v1 = *(const float4*)(src + 4);
            wreg[g][m][0]=v0.x; wreg[g][m][1]=v0.y; wreg[g][m][2]=v0.z; wreg[g][m][3]=v0.w;
            wreg[g][m][4]=v1.x; wreg[g][m][5]=v1.y; wreg[g][m][6]=v1.z; wreg[g][m][7]=v1.w;
        }

    int my_i = base_i + lane;   // meaningful for lane < 4
    float bh_r=0.f, bh_z=0.f, bh_n=0.f;
    float gr=0.f, gz=0.f, gn=0.f;
    float hv = 0.f;             // own h_prev[my_i], register-carried
    if (lane < 4) {
        bh_r = bhh[my_i]; bh_z = bhh[H_DIM + my_i]; bh_n = bhh[2*H_DIM + my_i];
        int t0 = fwd ? 0 : (S_LEN - 1);
        const float* g0 = gic + (size_t)t0 * G3;
        gr = g0[my_i]; gz = g0[H_DIM + my_i]; gn = g0[2*H_DIM + my_i];
    }

    float hf[8] = {0.f,0.f,0.f,0.f,0.f,0.f,0.f,0.f};   // h_0 = 0

    for (int s = 0; s < S_LEN; ++s) {
        int pb = s & 1;
        if (s > 0) {
            // Poll the 64 B this lane consumes: slots 8*lane .. 8*lane+8.
            const u64* src = hp + (size_t)pb * H_DIM + (size_t)lane * 8;
            const u64 a0 = (u64)(src + 0), a1 = (u64)(src + 2),
                      a2 = (u64)(src + 4), a3 = (u64)(src + 6);
            const u32 tg = (u32)s;
            u32x4 r0, r1, r2, r3;
            for (;;) {
                asm volatile(
                    "global_load_dwordx4 %0, %4, off sc0 sc1\n\t"
                    "global_load_dwordx4 %1, %5, off sc0 sc1\n\t"
                    "global_load_dwordx4 %2, %6, off sc0 sc1\n\t"
                    "global_load_dwordx4 %3, %7, off sc0 sc1\n\t"
                    "s_waitcnt vmcnt(0)"
                    : "=&v"(r0), "=&v"(r1), "=&v"(r2), "=&v"(r3)
                    : "v"(a0), "v"(a1), "v"(a2), "v"(a3)
                    : "memory");
                bool ok = (r0.y==tg) & (r0.w==tg) & (r1.y==tg) & (r1.w==tg) &
                          (r2.y==tg) & (r2.w==tg) & (r3.y==tg) & (r3.w==tg);
                if (ok) break;
            }
            hf[0]=__uint_as_float(r0.x); hf[1]=__uint_as_float(r0.z);
            hf[2]=__uint_as_float(r1.x); hf[3]=__uint_as_float(r1.z);
            hf[4]=__uint_as_float(r2.x); hf[5]=__uint_as_float(r2.z);
            hf[6]=__uint_as_float(r3.x); hf[7]=__uint_as_float(r3.z);
        }

        float acc[3][4];
        #pragma unroll
        for (int g = 0; g < 3; ++g)
            #pragma unroll
            for (int m = 0; m < 4; ++m) {
                float a = 0.f;
                #pragma unroll
                for (int e = 0; e < 8; ++e) a = fmaf(wreg[g][m][e], hf[e], a);
                acc[g][m] = a;
            }
        #pragma unroll
        for (int off = 32; off >= 1; off >>= 1)
            #pragma unroll
            for (int g = 0; g < 3; ++g)
                #pragma unroll
                for (int m = 0; m < 4; ++m)
                    acc[g][m] += __shfl_xor(acc[g][m], off, 64);

        if (lane < 4) {
            float ar = (lane==0)?acc[0][0]:(lane==1)?acc[0][1]:(lane==2)?acc[0][2]:acc[0][3];
            float az = (lane==0)?acc[1][0]:(lane==1)?acc[1][1]:(lane==2)?acc[1][2]:acc[1][3];
            float an = (lane==0)?acc[2][0]:(lane==1)?acc[2][1]:(lane==2)?acc[2][2]:acc[2][3];
            float rr = 1.f / (1.f + expf(-(gr + ar + bh_r)));
            float zz = 1.f / (1.f + expf(-(gz + az + bh_z)));
            float nn = tanhf(gn + rr * (an + bh_n));
            float hn = (1.f - zz) * nn + zz * hv;
            hv = hn;                                  // register carry for blend
            union { float f; u32 u; } cv; cv.f = hn;
            u64 pk = ((u64)(u32)(s + 1) << 32) | (u64)cv.u;
            __hip_atomic_store(hp + (size_t)(pb ^ 1) * H_DIM + my_i, pk,
                               __ATOMIC_RELAXED, __HIP_MEMORY_SCOPE_AGENT);
            if (s == S_LEN - 1)
                hfc[my_i] = hn;                       // final h for dense head
        }
        // Prefetch next step's gi (off critical path)
        if (lane < 4 && s + 1 < S_LEN) {
            int tn = fwd ? (s + 1) : (S_LEN - 2 - s);
            const float* gnx = gic + (size_t)tn * G3;
            gr = gnx[my_i]; gz = gnx[H_DIM + my_i]; gn = gnx[2*H_DIM + my_i];
        }
    }
}

// ---------------------------------------------------------------------------
// Phase 3a: h1 = relu(d1_w @ rep + d1_b); rep[j] = hfin[j] (chains concat).
// ---------------------------------------------------------------------------
__global__ __launch_bounds__(256) void dense1_kernel(
    const float* __restrict__ d1w, const float* __restrict__ d1b,
    const float* __restrict__ hfin, float* __restrict__ h1)
{
    int wv = threadIdx.x >> 6, lane = threadIdx.x & 63;
    int row = blockIdx.x * 4 + wv;
    const float* wr = d1w + (size_t)row * (4 * H_DIM);
    float sum = 0.f;
    #pragma unroll
    for (int q = 0; q < 32; ++q) {
        int j = lane + q * 64;
        sum = fmaf(wr[j], hfin[j], sum);
    }
    #pragma unroll
    for (int off = 32; off >= 1; off >>= 1) sum += __shfl_xor(sum, off, 64);
    if (lane == 0) h1[row] = fmaxf(sum + d1b[row], 0.f);
}

__global__ __launch_bounds__(256) void dense2_kernel(
    const float* __restrict__ d2w, const float* __restrict__ d2b,
    const float* __restrict__ h1, float* __restrict__ out)
{
    __shared__ float red[4];
    int tid = threadIdx.x, lane = tid & 63, wv = tid >> 6;
    float sum = 0.f;
    #pragma unroll
    for (int q = 0; q < 4; ++q) { int j = tid + q * 256; sum = fmaf(d2w[j], h1[j], sum); }
    #pragma unroll
    for (int off = 32; off >= 1; off >>= 1) sum += __shfl_xor(sum, off, 64);
    if (lane == 0) red[wv] = sum;
    __syncthreads();
    if (tid == 0) {
        float t = red[0] + red[1] + red[2] + red[3] + d2b[0];
        out[0] = 1.f / (1.f + expf(-t));
    }
}

// ---------------------------------------------------------------------------
extern "C" void kernel_launch(void* const* d_in, const int* in_sizes, int n_in,
                              void* d_out, int out_size, void* d_ws, size_t ws_size,
                              hipStream_t stream) {
    const int*   sent = (const int*)d_in[0];
    const float* emb  = (const float*)d_in[1];
    const float* Wih[4], *Whh[4], *bih[4], *bhh[4];
    for (int p = 0; p < 4; ++p) {
        Wih[p] = (const float*)d_in[2 + 4*p + 0];
        Whh[p] = (const float*)d_in[2 + 4*p + 1];
        bih[p] = (const float*)d_in[2 + 4*p + 2];
        bhh[p] = (const float*)d_in[2 + 4*p + 3];
    }
    const float* d1w = (const float*)d_in[18];
    const float* d1b = (const float*)d_in[19];
    const float* d2w = (const float*)d_in[20];
    const float* d2b = (const float*)d_in[21];
    float* out = (float*)d_out;

    // Workspace layout (bytes):
    //   gi   : 4*1024*1536*4 = 25165824
    //   hpk  : 4*2*512*8     = 32768   (tagged slots; 0xAA poison is harmless)
    //   hfin : 4*512*4       = 8192
    //   h1   : 1024*4        = 4096
    char* wsb = (char*)d_ws;
    float* gi   = (float*)wsb;                 wsb += (size_t)NCHAIN * S_LEN * G3 * sizeof(float);
    u64*   hpk  = (u64*)wsb;                   wsb += (size_t)NCHAIN * 2 * H_DIM * sizeof(u64);
    float* hfin = (float*)wsb;                 wsb += (size_t)NCHAIN * H_DIM * sizeof(float);
    float* h1   = (float*)wsb;

    gi_gemm_kernel<<<NCHAIN * (S_LEN/TM) * (G3/TN), 256, 0, stream>>>(
        sent, emb,
        Wih[0], bih[0], Wih[1], bih[1], Wih[2], bih[2], Wih[3], bih[3], gi);

    gru_scan_kernel<<<NCHAIN * WPC, 256, 0, stream>>>(
        Whh[0], bhh[0], Whh[1], bhh[1], Whh[2], bhh[2], Whh[3], bhh[3],
        gi, hpk, hfin);

    dense1_kernel<<<D_DIM / 4, 256, 0, stream>>>(d1w, d1b, hfin, h1);
    dense2_kernel<<<1, 256, 0, stream>>>(d2w, d2b, h1, out);
}

// Round 6
// 3194.964 us; speedup vs baseline: 3.0028x; 1.1200x over previous
//
#include <hip/hip_runtime.h>
#include <math.h>

typedef unsigned long long u64;
typedef unsigned int u32;
typedef unsigned int u32x4 __attribute__((ext_vector_type(4)));

#define S_LEN 1024
#define E_DIM 512
#define H_DIM 512
#define G3    1536   // 3*H
#define D_DIM 1024

#define NCHAIN 4
#define WPC    32    // workgroups per GRU chain (128 blocks total, co-resident)

// ---------------------------------------------------------------------------
// Phase 1: gi[p][t][j] = bih_p[j] + sum_k emb[sent[t],k] * Wih_p[j,k]
// Tiled fp32 GEMM (proven R2 version, unchanged).
// ---------------------------------------------------------------------------
#define TM 64
#define TN 64
#define BK 32

__global__ __launch_bounds__(256) void gi_gemm_kernel(
    const int* __restrict__ sent, const float* __restrict__ emb,
    const float* __restrict__ Wih0, const float* __restrict__ bih0,
    const float* __restrict__ Wih1, const float* __restrict__ bih1,
    const float* __restrict__ Wih2, const float* __restrict__ bih2,
    const float* __restrict__ Wih3, const float* __restrict__ bih3,
    float* __restrict__ gi)
{
    __shared__ float As[BK][TM + 1];
    __shared__ float Bs[BK][TN + 1];
    __shared__ int   rows[TM];

    const int blocks_t = S_LEN / TM;   // 16
    const int blocks_j = G3 / TN;      // 24
    int b   = blockIdx.x;
    int p   = b / (blocks_t * blocks_j);
    int rem = b % (blocks_t * blocks_j);
    int bt  = rem / blocks_j;
    int bj  = rem % blocks_j;

    const float* Wih = (p == 0) ? Wih0 : (p == 1) ? Wih1 : (p == 2) ? Wih2 : Wih3;
    const float* bih = (p == 0) ? bih0 : (p == 1) ? bih1 : (p == 2) ? bih2 : bih3;

    int tid = threadIdx.x;
    if (tid < TM) rows[tid] = sent[bt * TM + tid];
    __syncthreads();

    int tt = (tid >> 4) * 4;
    int jj = (tid & 15) * 4;
    float acc[4][4] = {{0.f}};

    int lr = tid >> 2;
    int lc = (tid & 3) * 8;

    for (int k0 = 0; k0 < E_DIM; k0 += BK) {
        const float* asrc = emb + (size_t)rows[lr] * E_DIM + (k0 + lc);
        float4 a0 = *(const float4*)asrc;
        float4 a1 = *(const float4*)(asrc + 4);
        const float* bsrc = Wih + (size_t)(bj * TN + lr) * E_DIM + (k0 + lc);
        float4 b0 = *(const float4*)bsrc;
        float4 b1 = *(const float4*)(bsrc + 4);

        As[lc+0][lr]=a0.x; As[lc+1][lr]=a0.y; As[lc+2][lr]=a0.z; As[lc+3][lr]=a0.w;
        As[lc+4][lr]=a1.x; As[lc+5][lr]=a1.y; As[lc+6][lr]=a1.z; As[lc+7][lr]=a1.w;
        Bs[lc+0][lr]=b0.x; Bs[lc+1][lr]=b0.y; Bs[lc+2][lr]=b0.z; Bs[lc+3][lr]=b0.w;
        Bs[lc+4][lr]=b1.x; Bs[lc+5][lr]=b1.y; Bs[lc+6][lr]=b1.z; Bs[lc+7][lr]=b1.w;
        __syncthreads();

        #pragma unroll
        for (int kk = 0; kk < BK; ++kk) {
            float av[4], bv[4];
            #pragma unroll
            for (int e = 0; e < 4; ++e) { av[e] = As[kk][tt+e]; bv[e] = Bs[kk][jj+e]; }
            #pragma unroll
            for (int i = 0; i < 4; ++i)
                #pragma unroll
                for (int j2 = 0; j2 < 4; ++j2)
                    acc[i][j2] = fmaf(av[i], bv[j2], acc[i][j2]);
        }
        __syncthreads();
    }

    float* gout = gi + (size_t)p * S_LEN * G3;
    int jbase = bj * TN + jj;
    float bb0 = bih[jbase+0], bb1 = bih[jbase+1], bb2 = bih[jbase+2], bb3 = bih[jbase+3];
    #pragma unroll
    for (int i = 0; i < 4; ++i) {
        int t = bt * TM + tt + i;
        float4 v = make_float4(acc[i][0]+bb0, acc[i][1]+bb1, acc[i][2]+bb2, acc[i][3]+bb3);
        *(float4*)(gout + (size_t)t * G3 + jbase) = v;
    }
}

// ---------------------------------------------------------------------------
// Phase 2: 4 GRU recurrences, persistent, tagged-slot sync with a dedicated
// RELAY WAVE per block (block = 320 threads = 4 compute waves + 1 relay).
//
// Protocol (R2/R5-proven medium): LLC tagged 8B slots {tag=step:u32, val:f32},
// agent-scope relaxed (sc0 sc1) stores/loads, parity double-buffer, fence-free.
//
// Pipeline: during iteration s, compute waves read h_s from LDS[pb] and
// publish h_{s+1} (tag s+1, parity pb^1); the relay wave CONCURRENTLY polls
// parity pb^1 for tag s+1 and stages it into LDS[pb^1]. One __syncthreads
// per iteration hands off. Critical path = max(detect, compute), not sum,
// and only 1 wave per block generates poll traffic (16x less than R5).
//
// Overwrite safety: a block stores tag s+3 (parity pb^1) only after its
// relay consumed all tags s+2, which requires every block's tag-s+2 store,
// which requires every relay consumed s+1. So slots holding tag s+1 are
// never overwritten before every relay consumed them.
// 0xAA workspace poison (tag 0xAAAAAAAA) never matches s in [1,1024].
// ---------------------------------------------------------------------------
__global__ __launch_bounds__(320) void gru_scan_kernel(
    const float* __restrict__ Whh0, const float* __restrict__ bhh0,
    const float* __restrict__ Whh1, const float* __restrict__ bhh1,
    const float* __restrict__ Whh2, const float* __restrict__ bhh2,
    const float* __restrict__ Whh3, const float* __restrict__ bhh3,
    const float* __restrict__ gi,
    u64* __restrict__ hpk,          // [4][2][512] tagged slots (no init needed)
    float* __restrict__ hfin)       // [4][512] final h
{
    __shared__ float lds_h[2][H_DIM];

    int b = blockIdx.x;
    int c = b / WPC;
    int w = b % WPC;
    const float* Whh = (c==0)?Whh0:(c==1)?Whh1:(c==2)?Whh2:Whh3;
    const float* bhh = (c==0)?bhh0:(c==1)?bhh1:(c==2)?bhh2:bhh3;
    const float* gic = gi + (size_t)c * S_LEN * G3;
    u64* hp = hpk + (size_t)c * 2 * H_DIM;
    float* hfc = hfin + (size_t)c * H_DIM;
    const bool fwd = ((c & 1) == 0);   // chains 0 (ctx_f), 2 (qry_f) forward

    int tid  = threadIdx.x;
    int wv   = tid >> 6;               // 0..3 compute, 4 relay
    int lane = tid & 63;

    for (int i = tid; i < H_DIM; i += 320) lds_h[0][i] = 0.f;   // h_0 = 0

    if (wv < 4) {
        // ---------------- compute wave ----------------
        int base_i = w * 16 + wv * 4;

        // Whh fragment: wreg[g][m][e] = Whh[g*512 + base_i + m][lane*8 + e]
        float wreg[3][4][8];
        #pragma unroll
        for (int g = 0; g < 3; ++g)
            #pragma unroll
            for (int m = 0; m < 4; ++m) {
                const float* src = Whh + (size_t)(g * H_DIM + base_i + m) * H_DIM + lane * 8;
                float4 v0 = *(const float4*)src;
                float4 v1 = *(const float4*)(src + 4);
                wreg[g][m][0]=v0.x; wreg[g][m][1]=v0.y; wreg[g][m][2]=v0.z; wreg[g][m][3]=v0.w;
                wreg[g][m][4]=v1.x; wreg[g][m][5]=v1.y; wreg[g][m][6]=v1.z; wreg[g][m][7]=v1.w;
            }

        int my_i = base_i + lane;   // meaningful for lane < 4
        float bh_r=0.f, bh_z=0.f, bh_n=0.f;
        float gr=0.f, gz=0.f, gn=0.f;
        float hv = 0.f;             // own h_prev[my_i], register-carried
        if (lane < 4) {
            bh_r = bhh[my_i]; bh_z = bhh[H_DIM + my_i]; bh_n = bhh[2*H_DIM + my_i];
            int t0 = fwd ? 0 : (S_LEN - 1);
            const float* g0 = gic + (size_t)t0 * G3;
            gr = g0[my_i]; gz = g0[H_DIM + my_i]; gn = g0[2*H_DIM + my_i];
        }
        __syncthreads();   // LDS[0] zeros visible

        for (int s = 0; s < S_LEN; ++s) {
            int pb = s & 1;
            float hf[8];
            #pragma unroll
            for (int e = 0; e < 8; ++e) hf[e] = lds_h[pb][lane * 8 + e];

            float acc[3][4];
            #pragma unroll
            for (int g = 0; g < 3; ++g)
                #pragma unroll
                for (int m = 0; m < 4; ++m) {
                    float a = 0.f;
                    #pragma unroll
                    for (int e = 0; e < 8; ++e) a = fmaf(wreg[g][m][e], hf[e], a);
                    acc[g][m] = a;
                }
            #pragma unroll
            for (int off = 32; off >= 1; off >>= 1)
                #pragma unroll
                for (int g = 0; g < 3; ++g)
                    #pragma unroll
                    for (int m = 0; m < 4; ++m)
                        acc[g][m] += __shfl_xor(acc[g][m], off, 64);

            if (lane < 4) {
                float ar = (lane==0)?acc[0][0]:(lane==1)?acc[0][1]:(lane==2)?acc[0][2]:acc[0][3];
                float az = (lane==0)?acc[1][0]:(lane==1)?acc[1][1]:(lane==2)?acc[1][2]:acc[1][3];
                float an = (lane==0)?acc[2][0]:(lane==1)?acc[2][1]:(lane==2)?acc[2][2]:acc[2][3];
                float rr = 1.f / (1.f + expf(-(gr + ar + bh_r)));
                float zz = 1.f / (1.f + expf(-(gz + az + bh_z)));
                float nn = tanhf(gn + rr * (an + bh_n));
                float hn = (1.f - zz) * nn + zz * hv;
                hv = hn;
                union { float f; u32 u; } cv; cv.f = hn;
                u64 pk = ((u64)(u32)(s + 1) << 32) | (u64)cv.u;
                __hip_atomic_store(hp + (size_t)(pb ^ 1) * H_DIM + my_i, pk,
                                   __ATOMIC_RELAXED, __HIP_MEMORY_SCOPE_AGENT);
                if (s == S_LEN - 1) hfc[my_i] = hn;
            }
            // Prefetch next step's gi (off critical path)
            if (lane < 4 && s + 1 < S_LEN) {
                int tn = fwd ? (s + 1) : (S_LEN - 2 - s);
                const float* gnx = gic + (size_t)tn * G3;
                gr = gnx[my_i]; gz = gnx[H_DIM + my_i]; gn = gnx[2*H_DIM + my_i];
            }
            __syncthreads();   // hand off: LDS[pb^1] now holds h_{s+1}
        }
    } else {
        // ---------------- relay wave ----------------
        __syncthreads();   // match compute's initial barrier

        for (int s = 0; s < S_LEN; ++s) {
            int pb = s & 1;
            if (s + 1 < S_LEN) {
                // Poll parity pb^1 for tag s+1: slots 8*lane .. 8*lane+8.
                const u64* src = hp + (size_t)(pb ^ 1) * H_DIM + (size_t)lane * 8;
                const u64 a0 = (u64)(src + 0), a1 = (u64)(src + 2),
                          a2 = (u64)(src + 4), a3 = (u64)(src + 6);
                const u32 tg = (u32)(s + 1);
                u32x4 r0, r1, r2, r3;
                for (;;) {
                    asm volatile(
                        "global_load_dwordx4 %0, %4, off sc0 sc1\n\t"
                        "global_load_dwordx4 %1, %5, off sc0 sc1\n\t"
                        "global_load_dwordx4 %2, %6, off sc0 sc1\n\t"
                        "global_load_dwordx4 %3, %7, off sc0 sc1\n\t"
                        "s_waitcnt vmcnt(0)"
                        : "=&v"(r0), "=&v"(r1), "=&v"(r2), "=&v"(r3)
                        : "v"(a0), "v"(a1), "v"(a2), "v"(a3)
                        : "memory");
                    bool ok = (r0.y==tg) & (r0.w==tg) & (r1.y==tg) & (r1.w==tg) &
                              (r2.y==tg) & (r2.w==tg) & (r3.y==tg) & (r3.w==tg);
                    if (ok) break;
                }
                float* dst = &lds_h[pb ^ 1][lane * 8];
                dst[0]=__uint_as_float(r0.x); dst[1]=__uint_as_float(r0.z);
                dst[2]=__uint_as_float(r1.x); dst[3]=__uint_as_float(r1.z);
                dst[4]=__uint_as_float(r2.x); dst[5]=__uint_as_float(r2.z);
                dst[6]=__uint_as_float(r3.x); dst[7]=__uint_as_float(r3.z);
            }
            __syncthreads();
        }
    }
}

// ---------------------------------------------------------------------------
// Phase 3a: h1 = relu(d1_w @ rep + d1_b); rep[j] = hfin[j] (chains concat).
// ---------------------------------------------------------------------------
__global__ __launch_bounds__(256) void dense1_kernel(
    const float* __restrict__ d1w, const float* __restrict__ d1b,
    const float* __restrict__ hfin, float* __restrict__ h1)
{
    int wv = threadIdx.x >> 6, lane = threadIdx.x & 63;
    int row = blockIdx.x * 4 + wv;
    const float* wr = d1w + (size_t)row * (4 * H_DIM);
    float sum = 0.f;
    #pragma unroll
    for (int q = 0; q < 32; ++q) {
        int j = lane + q * 64;
        sum = fmaf(wr[j], hfin[j], sum);
    }
    #pragma unroll
    for (int off = 32; off >= 1; off >>= 1) sum += __shfl_xor(sum, off, 64);
    if (lane == 0) h1[row] = fmaxf(sum + d1b[row], 0.f);
}

__global__ __launch_bounds__(256) void dense2_kernel(
    const float* __restrict__ d2w, const float* __restrict__ d2b,
    const float* __restrict__ h1, float* __restrict__ out)
{
    __shared__ float red[4];
    int tid = threadIdx.x, lane = tid & 63, wv = tid >> 6;
    float sum = 0.f;
    #pragma unroll
    for (int q = 0; q < 4; ++q) { int j = tid + q * 256; sum = fmaf(d2w[j], h1[j], sum); }
    #pragma unroll
    for (int off = 32; off >= 1; off >>= 1) sum += __shfl_xor(sum, off, 64);
    if (lane == 0) red[wv] = sum;
    __syncthreads();
    if (tid == 0) {
        float t = red[0] + red[1] + red[2] + red[3] + d2b[0];
        out[0] = 1.f / (1.f + expf(-t));
    }
}

// ---------------------------------------------------------------------------
extern "C" void kernel_launch(void* const* d_in, const int* in_sizes, int n_in,
                              void* d_out, int out_size, void* d_ws, size_t ws_size,
                              hipStream_t stream) {
    const int*   sent = (const int*)d_in[0];
    const float* emb  = (const float*)d_in[1];
    const float* Wih[4], *Whh[4], *bih[4], *bhh[4];
    for (int p = 0; p < 4; ++p) {
        Wih[p] = (const float*)d_in[2 + 4*p + 0];
        Whh[p] = (const float*)d_in[2 + 4*p + 1];
        bih[p] = (const float*)d_in[2 + 4*p + 2];
        bhh[p] = (const float*)d_in[2 + 4*p + 3];
    }
    const float* d1w = (const float*)d_in[18];
    const float* d1b = (const float*)d_in[19];
    const float* d2w = (const float*)d_in[20];
    const float* d2b = (const float*)d_in[21];
    float* out = (float*)d_out;

    // Workspace layout (bytes):
    //   gi   : 4*1024*1536*4 = 25165824
    //   hpk  : 4*2*512*8     = 32768   (tagged slots; 0xAA poison harmless)
    //   hfin : 4*512*4       = 8192
    //   h1   : 1024*4        = 4096
    char* wsb = (char*)d_ws;
    float* gi   = (float*)wsb;                 wsb += (size_t)NCHAIN * S_LEN * G3 * sizeof(float);
    u64*   hpk  = (u64*)wsb;                   wsb += (size_t)NCHAIN * 2 * H_DIM * sizeof(u64);
    float* hfin = (float*)wsb;                 wsb += (size_t)NCHAIN * H_DIM * sizeof(float);
    float* h1   = (float*)wsb;

    gi_gemm_kernel<<<NCHAIN * (S_LEN/TM) * (G3/TN), 256, 0, stream>>>(
        sent, emb,
        Wih[0], bih[0], Wih[1], bih[1], Wih[2], bih[2], Wih[3], bih[3], gi);

    gru_scan_kernel<<<NCHAIN * WPC, 320, 0, stream>>>(
        Whh[0], bhh[0], Whh[1], bhh[1], Whh[2], bhh[2], Whh[3], bhh[3],
        gi, hpk, hfin);

    dense1_kernel<<<D_DIM / 4, 256, 0, stream>>>(d1w, d1b, hfin, h1);
    dense2_kernel<<<1, 256, 0, stream>>>(d2w, d2b, h1, out);
}